// Round 6
// baseline (9717.678 us; speedup 1.0000x reference)
//
#include <hip/hip_runtime.h>
#include <cstdint>
#include <cstddef>

#define DD 128
#define ATS 68    // At row stride (64 rows + 4 pad)
#define BQS 132   // B-quarter row stride

// ---------------- CSR build (both graphs in one launch) ----------------

__global__ void count2_k(const int* __restrict__ dstb, const int* __restrict__ dstg,
                         int* __restrict__ degb, int* __restrict__ degg, int E, int gE) {
    int b = blockIdx.x;
    const int* dst = (b < gE) ? dstb : dstg;
    int* deg = (b < gE) ? degb : degg;
    int i = ((b < gE) ? b : b - gE) * blockDim.x + threadIdx.x;
    if (i < E) atomicAdd(&deg[dst[i]], 1);
}

__global__ __launch_bounds__(1024) void scan2_k(const int* __restrict__ degb,
                                                const int* __restrict__ degg,
                                                int* __restrict__ rpb, int* __restrict__ rpg,
                                                int* __restrict__ curb, int* __restrict__ curg,
                                                int n) {
    const int* deg = (blockIdx.x == 0) ? degb : degg;
    int* rp = (blockIdx.x == 0) ? rpb : rpg;
    int* cur = (blockIdx.x == 0) ? curb : curg;
    __shared__ int sums[1024];
    int tid = threadIdx.x;
    int per = (n + 1023) >> 10;
    int start = tid * per;
    int end = min(start + per, n);
    int s = 0;
    for (int i = start; i < end; ++i) s += deg[i];
    sums[tid] = s;
    __syncthreads();
    for (int off = 1; off < 1024; off <<= 1) {
        int v = (tid >= off) ? sums[tid - off] : 0;
        __syncthreads();
        sums[tid] += v;
        __syncthreads();
    }
    int pre = (tid == 0) ? 0 : sums[tid - 1];
    for (int i = start; i < end; ++i) {
        rp[i] = pre;
        cur[i] = pre;
        pre += deg[i];
    }
    if (end == n) rp[n] = pre;
}

__global__ void fill2_k(const int* __restrict__ srcb, const int* __restrict__ dstb,
                        const float* __restrict__ wb,
                        const int* __restrict__ srcg, const int* __restrict__ dstg,
                        const float* __restrict__ wg,
                        int* __restrict__ curb, int* __restrict__ curg,
                        int2* __restrict__ eb, int2* __restrict__ eg, int E, int gE) {
    int b = blockIdx.x;
    bool isb = (b < gE);
    const int* src = isb ? srcb : srcg;
    const int* dst = isb ? dstb : dstg;
    const float* w = isb ? wb : wg;
    int* cur = isb ? curb : curg;
    int2* edges = isb ? eb : eg;
    int i = (isb ? b : b - gE) * blockDim.x + threadIdx.x;
    if (i < E) {
        int d = dst[i];
        int pos = atomicAdd(&cur[d], 1);
        edges[pos] = make_int2(src[i], __float_as_int(w[i]));
    }
}

// ---------------- P = H H^T, S = H + H^T ----------------

__global__ __launch_bounds__(256) void prep_k(const float* __restrict__ H,
                                              float* __restrict__ P,
                                              float* __restrict__ S) {
    int idx = blockIdx.x * 256 + threadIdx.x;
    int i = idx >> 7, j = idx & 127;
    float acc = 0.f;
    for (int k = 0; k < DD; ++k) acc += H[i * DD + k] * H[j * DD + k];
    P[idx] = acc;
    S[idx] = H[i * DD + j] + H[j * DD + i];
}

// ---------------- device helpers ----------------

__device__ __forceinline__ void gather_row(const int* __restrict__ rp,
                                           const int2* __restrict__ edges,
                                           const float* __restrict__ Y,
                                           float* __restrict__ out,
                                           int node, int lane) {
    int beg = rp[node], end = rp[node + 1];
    float a0 = 0.f, a1 = 0.f;
    int j = beg;
    for (; j + 8 <= end; j += 8) {
        int2 e0 = edges[j + 0], e1 = edges[j + 1], e2 = edges[j + 2], e3 = edges[j + 3];
        int2 e4 = edges[j + 4], e5 = edges[j + 5], e6 = edges[j + 6], e7 = edges[j + 7];
        float2 f0 = *((const float2*)(Y + (size_t)e0.x * DD) + lane);
        float2 f1 = *((const float2*)(Y + (size_t)e1.x * DD) + lane);
        float2 f2 = *((const float2*)(Y + (size_t)e2.x * DD) + lane);
        float2 f3 = *((const float2*)(Y + (size_t)e3.x * DD) + lane);
        float2 f4 = *((const float2*)(Y + (size_t)e4.x * DD) + lane);
        float2 f5 = *((const float2*)(Y + (size_t)e5.x * DD) + lane);
        float2 f6 = *((const float2*)(Y + (size_t)e6.x * DD) + lane);
        float2 f7 = *((const float2*)(Y + (size_t)e7.x * DD) + lane);
        float w0 = __int_as_float(e0.y), w1 = __int_as_float(e1.y);
        float w2 = __int_as_float(e2.y), w3 = __int_as_float(e3.y);
        float w4 = __int_as_float(e4.y), w5 = __int_as_float(e5.y);
        float w6 = __int_as_float(e6.y), w7 = __int_as_float(e7.y);
        a0 += w0 * f0.x; a1 += w0 * f0.y;
        a0 += w1 * f1.x; a1 += w1 * f1.y;
        a0 += w2 * f2.x; a1 += w2 * f2.y;
        a0 += w3 * f3.x; a1 += w3 * f3.y;
        a0 += w4 * f4.x; a1 += w4 * f4.y;
        a0 += w5 * f5.x; a1 += w5 * f5.y;
        a0 += w6 * f6.x; a1 += w6 * f6.y;
        a0 += w7 * f7.x; a1 += w7 * f7.y;
    }
    for (; j + 4 <= end; j += 4) {
        int2 e0 = edges[j + 0], e1 = edges[j + 1], e2 = edges[j + 2], e3 = edges[j + 3];
        float2 f0 = *((const float2*)(Y + (size_t)e0.x * DD) + lane);
        float2 f1 = *((const float2*)(Y + (size_t)e1.x * DD) + lane);
        float2 f2 = *((const float2*)(Y + (size_t)e2.x * DD) + lane);
        float2 f3 = *((const float2*)(Y + (size_t)e3.x * DD) + lane);
        float w0 = __int_as_float(e0.y), w1 = __int_as_float(e1.y);
        float w2 = __int_as_float(e2.y), w3 = __int_as_float(e3.y);
        a0 += w0 * f0.x; a1 += w0 * f0.y;
        a0 += w1 * f1.x; a1 += w1 * f1.y;
        a0 += w2 * f2.x; a1 += w2 * f2.y;
        a0 += w3 * f3.x; a1 += w3 * f3.y;
    }
    for (; j < end; ++j) {
        int2 e = edges[j];
        float2 f = *((const float2*)(Y + (size_t)e.x * DD) + lane);
        float wv = __int_as_float(e.y);
        a0 += wv * f.x; a1 += wv * f.y;
    }
    *((float2*)(out + (size_t)node * DD) + lane) = make_float2(a0, a1);
}

// ---------------- k1: mixed-role (spmm both graphs | P-dense -> R) ----------------
// role: (bid & 15)==15 -> dense, else spmm. spmm id = bid - bid/16.
// dense: At <- Y^T tile, aP1 = Y@P1, aP2 = Y@P2 (shared A stage),
//        R = X + dg*Y - db*aP1 - dg*aP2

__global__ __launch_bounds__(256, 3) void k1_mixed(
    const float* __restrict__ Yc, const float* __restrict__ X,
    const int* __restrict__ rpb, const int2* __restrict__ eb,
    const int* __restrict__ rpg, const int2* __restrict__ eg,
    const float* __restrict__ db, const float* __restrict__ dg,
    const float* __restrict__ P1, const float* __restrict__ P2,
    float* __restrict__ AbY, float* __restrict__ AgY,
    float* __restrict__ R, int n, int nd)
{
    __shared__ float At[DD * ATS];
    __shared__ float U[32 * BQS];

    const int bid = blockIdx.x;
    const int tid = threadIdx.x;

    if ((bid & 15) != 15) {
        // ---- spmm role ----
        int sbid = bid - (bid >> 4);
        int node = sbid * 4 + (tid >> 6);
        if (node >= n) return;
        int lane = tid & 63;
        gather_row(rpb, eb, Yc, AbY, node, lane);
        gather_row(rpg, eg, Yc, AgY, node, lane);
        return;
    }

    // ---- dense P role ----
    int dbid = bid >> 4;
    if (dbid >= nd) return;
    const int cg = tid & 15;
    const int rg = tid >> 4;
    const int row0 = dbid * 64;

    float aP1[4][8], aP2[4][8];
#pragma unroll
    for (int i = 0; i < 4; ++i)
#pragma unroll
        for (int j = 0; j < 8; ++j) { aP1[i][j] = 0.f; aP2[i][j] = 0.f; }

    // stage Y tile transposed
    {
        int r = tid >> 2;
        int rowc = min(row0 + r, n - 1);
        const float* gp = Yc + (size_t)rowc * DD;
#pragma unroll
        for (int i = 0; i < 8; ++i) {
            int c = ((tid & 3) << 2) + (i << 4);
            float4 v = *reinterpret_cast<const float4*>(gp + c);
            At[(c + 0) * ATS + r] = v.x;
            At[(c + 1) * ATS + r] = v.y;
            At[(c + 2) * ATS + r] = v.z;
            At[(c + 3) * ATS + r] = v.w;
        }
    }
    __syncthreads();

    auto gemm = [&](const float* __restrict__ M, float (&acc)[4][8]) {
#pragma unroll 1
        for (int kq = 0; kq < 4; ++kq) {
            {
                int kl = tid & 31;
                int cb = (tid >> 5) * 16;
                const float* gp = M + (size_t)(kq * 32 + kl) * DD + cb;
                float* bp = U + kl * BQS + cb;
#pragma unroll
                for (int u = 0; u < 4; ++u)
                    *reinterpret_cast<float4*>(bp + 4 * u) =
                        *reinterpret_cast<const float4*>(gp + 4 * u);
            }
            __syncthreads();
#pragma unroll 2
            for (int kl = 0; kl < 32; ++kl) {
                int k = kq * 32 + kl;
                float4 a = *reinterpret_cast<const float4*>(&At[k * ATS + rg * 4]);
                float4 b0 = *reinterpret_cast<const float4*>(&U[kl * BQS + cg * 4]);
                float4 b1 = *reinterpret_cast<const float4*>(&U[kl * BQS + 64 + cg * 4]);
                float av[4] = {a.x, a.y, a.z, a.w};
                float bv[8] = {b0.x, b0.y, b0.z, b0.w, b1.x, b1.y, b1.z, b1.w};
#pragma unroll
                for (int i = 0; i < 4; ++i)
#pragma unroll
                    for (int j = 0; j < 8; ++j) acc[i][j] += av[i] * bv[j];
            }
            __syncthreads();
        }
    };

    gemm(P1, aP1);
    gemm(P2, aP2);

    // R = X + dg*Y - db*aP1 - dg*aP2
#pragma unroll
    for (int i = 0; i < 4; ++i) {
        int row = row0 + rg * 4 + i;
        if (row < n) {
            float dbv = db[row], dgv = dg[row];
#pragma unroll
            for (int hh = 0; hh < 2; ++hh) {
                size_t off = (size_t)row * DD + hh * 64 + cg * 4;
                float4 y = *reinterpret_cast<const float4*>(Yc + off);
                float4 x = *reinterpret_cast<const float4*>(X + off);
                float yv[4] = {y.x, y.y, y.z, y.w};
                float xv[4] = {x.x, x.y, x.z, x.w};
                float ov[4];
#pragma unroll
                for (int q = 0; q < 4; ++q) {
                    int j = hh * 4 + q;
                    ov[q] = xv[q] + dgv * yv[q] - dbv * aP1[i][j] - dgv * aP2[i][j];
                }
                *reinterpret_cast<float4*>(R + off) = make_float4(ov[0], ov[1], ov[2], ov[3]);
            }
        }
    }
}

// ---------------- k2: S-GEMMs + epilogue ----------------
// aS = AbY@S1 + AgY@S2 - AgY ; Yn = (2/3)Y + (1/3)(aS + R)/(db+dg+1)

__global__ __launch_bounds__(256, 3) void k2_sgemm(
    const float* __restrict__ Yc, const float* __restrict__ AbY,
    const float* __restrict__ AgY, const float* __restrict__ R,
    const float* __restrict__ db, const float* __restrict__ dg,
    const float* __restrict__ S1, const float* __restrict__ S2,
    float* __restrict__ Yn, int n)
{
    __shared__ float At[DD * ATS];
    __shared__ float U[32 * BQS];

    const int tid = threadIdx.x;
    const int cg = tid & 15;
    const int rg = tid >> 4;
    const int row0 = blockIdx.x * 64;

    float aS[4][8];
#pragma unroll
    for (int i = 0; i < 4; ++i)
#pragma unroll
        for (int j = 0; j < 8; ++j) aS[i][j] = 0.f;

    auto stageT = [&](const float* __restrict__ G) {
        int r = tid >> 2;
        int rowc = min(row0 + r, n - 1);
        const float* gp = G + (size_t)rowc * DD;
#pragma unroll
        for (int i = 0; i < 8; ++i) {
            int c = ((tid & 3) << 2) + (i << 4);
            float4 v = *reinterpret_cast<const float4*>(gp + c);
            At[(c + 0) * ATS + r] = v.x;
            At[(c + 1) * ATS + r] = v.y;
            At[(c + 2) * ATS + r] = v.z;
            At[(c + 3) * ATS + r] = v.w;
        }
    };
    auto gemm = [&](const float* __restrict__ M, float (&acc)[4][8]) {
#pragma unroll 1
        for (int kq = 0; kq < 4; ++kq) {
            {
                int kl = tid & 31;
                int cb = (tid >> 5) * 16;
                const float* gp = M + (size_t)(kq * 32 + kl) * DD + cb;
                float* bp = U + kl * BQS + cb;
#pragma unroll
                for (int u = 0; u < 4; ++u)
                    *reinterpret_cast<float4*>(bp + 4 * u) =
                        *reinterpret_cast<const float4*>(gp + 4 * u);
            }
            __syncthreads();
#pragma unroll 2
            for (int kl = 0; kl < 32; ++kl) {
                int k = kq * 32 + kl;
                float4 a = *reinterpret_cast<const float4*>(&At[k * ATS + rg * 4]);
                float4 b0 = *reinterpret_cast<const float4*>(&U[kl * BQS + cg * 4]);
                float4 b1 = *reinterpret_cast<const float4*>(&U[kl * BQS + 64 + cg * 4]);
                float av[4] = {a.x, a.y, a.z, a.w};
                float bv[8] = {b0.x, b0.y, b0.z, b0.w, b1.x, b1.y, b1.z, b1.w};
#pragma unroll
                for (int i = 0; i < 4; ++i)
#pragma unroll
                    for (int j = 0; j < 8; ++j) acc[i][j] += av[i] * bv[j];
            }
            __syncthreads();
        }
    };

    stageT(AbY);
    __syncthreads();
    gemm(S1, aS);

    stageT(AgY);
    __syncthreads();
    gemm(S2, aS);

    // aS -= AgY (still transposed in At)
#pragma unroll
    for (int i = 0; i < 4; ++i) {
        int r = rg * 4 + i;
#pragma unroll
        for (int j = 0; j < 8; ++j) {
            int c = (j >> 2) * 64 + cg * 4 + (j & 3);
            aS[i][j] -= At[c * ATS + r];
        }
    }

    const float AL = 1.0f / 3.0f;
#pragma unroll
    for (int i = 0; i < 4; ++i) {
        int row = row0 + rg * 4 + i;
        if (row < n) {
            float dbv = db[row], dgv = dg[row];
            float aq = AL / (dbv + dgv + 1.0f);
#pragma unroll
            for (int hh = 0; hh < 2; ++hh) {
                size_t off = (size_t)row * DD + hh * 64 + cg * 4;
                float4 y = *reinterpret_cast<const float4*>(Yc + off);
                float4 rr = *reinterpret_cast<const float4*>(R + off);
                float yv[4] = {y.x, y.y, y.z, y.w};
                float rv[4] = {rr.x, rr.y, rr.z, rr.w};
                float ov[4];
#pragma unroll
                for (int q = 0; q < 4; ++q) {
                    int j = hh * 4 + q;
                    ov[q] = (1.0f - AL) * yv[q] + (aS[i][j] + rv[q]) * aq;
                }
                *reinterpret_cast<float4*>(Yn + off) = make_float4(ov[0], ov[1], ov[2], ov[3]);
            }
        }
    }
}

// ---------------- host ----------------

extern "C" void kernel_launch(void* const* d_in, const int* in_sizes, int n_in,
                              void* d_out, int out_size, void* d_ws, size_t ws_size,
                              hipStream_t stream) {
    const float* X   = (const float*)d_in[0];
    const float* H1  = (const float*)d_in[1];
    const float* H2  = (const float*)d_in[2];
    const float* wb  = (const float*)d_in[3];
    const float* wg  = (const float*)d_in[4];
    const float* db  = (const float*)d_in[5];
    const float* dg  = (const float*)d_in[6];
    const int* srcb  = (const int*)d_in[7];
    const int* dstb  = (const int*)d_in[8];
    const int* srcg  = (const int*)d_in[9];
    const int* dstg  = (const int*)d_in[10];
    const int N = in_sizes[5];
    const int E = in_sizes[3];
    float* Yout = (float*)d_out;

    char* p = (char*)d_ws;
    auto alloc = [&](size_t b) -> void* {
        void* r = (void*)p;
        p += (b + 255) & ~(size_t)255;
        return r;
    };
    float* P1 = (float*)alloc((size_t)DD * DD * 4);
    float* S1 = (float*)alloc((size_t)DD * DD * 4);
    float* P2 = (float*)alloc((size_t)DD * DD * 4);
    float* S2 = (float*)alloc((size_t)DD * DD * 4);
    int* degb = (int*)alloc((size_t)N * 4);
    int* degg = (int*)alloc((size_t)N * 4);
    int* rpb  = (int*)alloc((size_t)(N + 1) * 4);
    int* rpg  = (int*)alloc((size_t)(N + 1) * 4);
    int* curb = (int*)alloc((size_t)N * 4);
    int* curg = (int*)alloc((size_t)N * 4);
    int2* eb  = (int2*)alloc((size_t)E * 8);
    int2* eg  = (int2*)alloc((size_t)E * 8);
    float* AbY = (float*)alloc((size_t)N * DD * 4);
    float* AgY = (float*)alloc((size_t)N * DD * 4);
    float* Rt  = (float*)alloc((size_t)N * DD * 4);
    float* Yw  = (float*)alloc((size_t)N * DD * 4);

    hipMemsetAsync(degb, 0, (size_t)N * 4, stream);
    hipMemsetAsync(degg, 0, (size_t)N * 4, stream);

    int gE = (E + 255) / 256;
    count2_k<<<2 * gE, 256, 0, stream>>>(dstb, dstg, degb, degg, E, gE);
    scan2_k<<<2, 1024, 0, stream>>>(degb, degg, rpb, rpg, curb, curg, N);
    fill2_k<<<2 * gE, 256, 0, stream>>>(srcb, dstb, wb, srcg, dstg, wg,
                                        curb, curg, eb, eg, E, gE);
    prep_k<<<64, 256, 0, stream>>>(H1, P1, S1);
    prep_k<<<64, 256, 0, stream>>>(H2, P2, S2);

    const float* Ycur = X;
    float* Ybufs[2] = {Yw, Yout};
    int gd = (N + 63) / 64;              // dense tiles
    int ns = (N + 3) / 4;                // spmm blocks needed
    long long T = ((long long)ns * 16 + 14) / 15;   // total k1 blocks (1/16 dense)
    if (T / 16 < gd) T = (long long)gd * 16;
    for (int s = 0; s < 8; ++s) {
        float* Yn = Ybufs[s & 1];
        k1_mixed<<<(int)T, 256, 0, stream>>>(Ycur, X, rpb, eb, rpg, eg, db, dg,
                                             P1, P2, AbY, AgY, Rt, N, gd);
        k2_sgemm<<<gd, 256, 0, stream>>>(Ycur, AbY, AgY, Rt, db, dg,
                                         S1, S2, Yn, N);
        Ycur = Yn;
    }
}

// Round 7
// 3954.504 us; speedup vs baseline: 2.4574x; 2.4574x over previous
//
#include <hip/hip_runtime.h>
#include <cstdint>
#include <cstddef>

#define DD 128
#define ATS 68    // At row stride (64 rows + 4 pad)
#define BQS 132   // B-quarter row stride

// ---------------- CSR build (both graphs in one launch) ----------------

__global__ void count2_k(const int* __restrict__ dstb, const int* __restrict__ dstg,
                         int* __restrict__ degb, int* __restrict__ degg, int E, int gE) {
    int b = blockIdx.x;
    const int* dst = (b < gE) ? dstb : dstg;
    int* deg = (b < gE) ? degb : degg;
    int i = ((b < gE) ? b : b - gE) * blockDim.x + threadIdx.x;
    if (i < E) atomicAdd(&deg[dst[i]], 1);
}

__global__ __launch_bounds__(1024) void scan2_k(const int* __restrict__ degb,
                                                const int* __restrict__ degg,
                                                int* __restrict__ rpb, int* __restrict__ rpg,
                                                int* __restrict__ curb, int* __restrict__ curg,
                                                int n) {
    const int* deg = (blockIdx.x == 0) ? degb : degg;
    int* rp = (blockIdx.x == 0) ? rpb : rpg;
    int* cur = (blockIdx.x == 0) ? curb : curg;
    __shared__ int sums[1024];
    int tid = threadIdx.x;
    int per = (n + 1023) >> 10;
    int start = tid * per;
    int end = min(start + per, n);
    int s = 0;
    for (int i = start; i < end; ++i) s += deg[i];
    sums[tid] = s;
    __syncthreads();
    for (int off = 1; off < 1024; off <<= 1) {
        int v = (tid >= off) ? sums[tid - off] : 0;
        __syncthreads();
        sums[tid] += v;
        __syncthreads();
    }
    int pre = (tid == 0) ? 0 : sums[tid - 1];
    for (int i = start; i < end; ++i) {
        rp[i] = pre;
        cur[i] = pre;
        pre += deg[i];
    }
    if (end == n) rp[n] = pre;
}

__global__ void fill2_k(const int* __restrict__ srcb, const int* __restrict__ dstb,
                        const float* __restrict__ wb,
                        const int* __restrict__ srcg, const int* __restrict__ dstg,
                        const float* __restrict__ wg,
                        int* __restrict__ curb, int* __restrict__ curg,
                        int2* __restrict__ eb, int2* __restrict__ eg, int E, int gE) {
    int b = blockIdx.x;
    bool isb = (b < gE);
    const int* src = isb ? srcb : srcg;
    const int* dst = isb ? dstb : dstg;
    const float* w = isb ? wb : wg;
    int* cur = isb ? curb : curg;
    int2* edges = isb ? eb : eg;
    int i = (isb ? b : b - gE) * blockDim.x + threadIdx.x;
    if (i < E) {
        int d = dst[i];
        int pos = atomicAdd(&cur[d], 1);
        edges[pos] = make_int2(src[i], __float_as_int(w[i]));
    }
}

// ---------------- P = H H^T, S = H + H^T ----------------

__global__ __launch_bounds__(256) void prep_k(const float* __restrict__ H,
                                              float* __restrict__ P,
                                              float* __restrict__ S) {
    int idx = blockIdx.x * 256 + threadIdx.x;
    int i = idx >> 7, j = idx & 127;
    float acc = 0.f;
    for (int k = 0; k < DD; ++k) acc += H[i * DD + k] * H[j * DD + k];
    P[idx] = acc;
    S[idx] = H[i * DD + j] + H[j * DD + i];
}

// ---------------- spmm2: both graphs, interleaved gather chains ----------------
// 1 wave per node; dual 4-deep pipelines (beta+gamma) = 8 outstanding row loads.
// No LDS; VGPR target <=64 for 8 waves/SIMD.

__global__ __launch_bounds__(256, 8) void spmm2_k(
    const int* __restrict__ rpb, const int2* __restrict__ eb,
    const int* __restrict__ rpg, const int2* __restrict__ eg,
    const float* __restrict__ Y,
    float* __restrict__ outb, float* __restrict__ outg, int n)
{
    int node = blockIdx.x * 4 + (threadIdx.x >> 6);
    if (node >= n) return;
    int lane = threadIdx.x & 63;

    int jb = rpb[node], be = rpb[node + 1];
    int jg = rpg[node], ge = rpg[node + 1];
    float b0 = 0.f, b1 = 0.f, g0 = 0.f, g1 = 0.f;

    // interleaved phase: 4 beta + 4 gamma in flight
    while (jb + 4 <= be && jg + 4 <= ge) {
        int2 x0 = eb[jb + 0], x1 = eb[jb + 1], x2 = eb[jb + 2], x3 = eb[jb + 3];
        int2 y0 = eg[jg + 0], y1 = eg[jg + 1], y2 = eg[jg + 2], y3 = eg[jg + 3];
        float2 fb0 = *((const float2*)(Y + (size_t)x0.x * DD) + lane);
        float2 fb1 = *((const float2*)(Y + (size_t)x1.x * DD) + lane);
        float2 fb2 = *((const float2*)(Y + (size_t)x2.x * DD) + lane);
        float2 fb3 = *((const float2*)(Y + (size_t)x3.x * DD) + lane);
        float2 fg0 = *((const float2*)(Y + (size_t)y0.x * DD) + lane);
        float2 fg1 = *((const float2*)(Y + (size_t)y1.x * DD) + lane);
        float2 fg2 = *((const float2*)(Y + (size_t)y2.x * DD) + lane);
        float2 fg3 = *((const float2*)(Y + (size_t)y3.x * DD) + lane);
        float wb0 = __int_as_float(x0.y), wb1 = __int_as_float(x1.y);
        float wb2 = __int_as_float(x2.y), wb3 = __int_as_float(x3.y);
        float wg0 = __int_as_float(y0.y), wg1 = __int_as_float(y1.y);
        float wg2 = __int_as_float(y2.y), wg3 = __int_as_float(y3.y);
        b0 += wb0 * fb0.x; b1 += wb0 * fb0.y;
        b0 += wb1 * fb1.x; b1 += wb1 * fb1.y;
        b0 += wb2 * fb2.x; b1 += wb2 * fb2.y;
        b0 += wb3 * fb3.x; b1 += wb3 * fb3.y;
        g0 += wg0 * fg0.x; g1 += wg0 * fg0.y;
        g0 += wg1 * fg1.x; g1 += wg1 * fg1.y;
        g0 += wg2 * fg2.x; g1 += wg2 * fg2.y;
        g0 += wg3 * fg3.x; g1 += wg3 * fg3.y;
        jb += 4; jg += 4;
    }
    // drain beta 4-deep
    while (jb + 4 <= be) {
        int2 x0 = eb[jb + 0], x1 = eb[jb + 1], x2 = eb[jb + 2], x3 = eb[jb + 3];
        float2 f0 = *((const float2*)(Y + (size_t)x0.x * DD) + lane);
        float2 f1 = *((const float2*)(Y + (size_t)x1.x * DD) + lane);
        float2 f2 = *((const float2*)(Y + (size_t)x2.x * DD) + lane);
        float2 f3 = *((const float2*)(Y + (size_t)x3.x * DD) + lane);
        float w0 = __int_as_float(x0.y), w1 = __int_as_float(x1.y);
        float w2 = __int_as_float(x2.y), w3 = __int_as_float(x3.y);
        b0 += w0 * f0.x; b1 += w0 * f0.y;
        b0 += w1 * f1.x; b1 += w1 * f1.y;
        b0 += w2 * f2.x; b1 += w2 * f2.y;
        b0 += w3 * f3.x; b1 += w3 * f3.y;
        jb += 4;
    }
    // drain gamma 4-deep
    while (jg + 4 <= ge) {
        int2 y0 = eg[jg + 0], y1 = eg[jg + 1], y2 = eg[jg + 2], y3 = eg[jg + 3];
        float2 f0 = *((const float2*)(Y + (size_t)y0.x * DD) + lane);
        float2 f1 = *((const float2*)(Y + (size_t)y1.x * DD) + lane);
        float2 f2 = *((const float2*)(Y + (size_t)y2.x * DD) + lane);
        float2 f3 = *((const float2*)(Y + (size_t)y3.x * DD) + lane);
        float w0 = __int_as_float(y0.y), w1 = __int_as_float(y1.y);
        float w2 = __int_as_float(y2.y), w3 = __int_as_float(y3.y);
        g0 += w0 * f0.x; g1 += w0 * f0.y;
        g0 += w1 * f1.x; g1 += w1 * f1.y;
        g0 += w2 * f2.x; g1 += w2 * f2.y;
        g0 += w3 * f3.x; g1 += w3 * f3.y;
        jg += 4;
    }
    for (; jb < be; ++jb) {
        int2 e = eb[jb];
        float2 f = *((const float2*)(Y + (size_t)e.x * DD) + lane);
        float wv = __int_as_float(e.y);
        b0 += wv * f.x; b1 += wv * f.y;
    }
    for (; jg < ge; ++jg) {
        int2 e = eg[jg];
        float2 f = *((const float2*)(Y + (size_t)e.x * DD) + lane);
        float wv = __int_as_float(e.y);
        g0 += wv * f.x; g1 += wv * f.y;
    }
    *((float2*)(outb + (size_t)node * DD) + lane) = make_float2(b0, b1);
    *((float2*)(outg + (size_t)node * DD) + lane) = make_float2(g0, g1);
}

// ---------------- dense4: all four GEMMs + epilogue (k2-proven structure) ----------------
// aS = AbY@S1 + AgY@S2 - AgY ; aP1 = Y@P1 ; aP2 = Y@P2
// Yn = (2/3)Y + (1/3)(aS + X + dg*Y - db*aP1 - dg*aP2)/(db+dg+1)

__global__ __launch_bounds__(256, 3) void dense4_k(
    const float* __restrict__ Yc, const float* __restrict__ X,
    const float* __restrict__ AbY, const float* __restrict__ AgY,
    const float* __restrict__ db, const float* __restrict__ dg,
    const float* __restrict__ P1, const float* __restrict__ P2,
    const float* __restrict__ S1, const float* __restrict__ S2,
    float* __restrict__ Yn, int n)
{
    __shared__ float At[DD * ATS];
    __shared__ float U[32 * BQS];

    const int tid = threadIdx.x;
    const int cg = tid & 15;
    const int rg = tid >> 4;
    const int row0 = blockIdx.x * 64;

    float aS[4][8], aP1[4][8], aP2[4][8];
#pragma unroll
    for (int i = 0; i < 4; ++i)
#pragma unroll
        for (int j = 0; j < 8; ++j) { aS[i][j] = 0.f; aP1[i][j] = 0.f; aP2[i][j] = 0.f; }

    auto stageT = [&](const float* __restrict__ G) {
        int r = tid >> 2;
        int rowc = min(row0 + r, n - 1);
        const float* gp = G + (size_t)rowc * DD;
#pragma unroll
        for (int i = 0; i < 8; ++i) {
            int c = ((tid & 3) << 2) + (i << 4);
            float4 v = *reinterpret_cast<const float4*>(gp + c);
            At[(c + 0) * ATS + r] = v.x;
            At[(c + 1) * ATS + r] = v.y;
            At[(c + 2) * ATS + r] = v.z;
            At[(c + 3) * ATS + r] = v.w;
        }
    };
    auto gemm = [&](const float* __restrict__ M, float (&acc)[4][8]) {
#pragma unroll 1
        for (int kq = 0; kq < 4; ++kq) {
            {
                int kl = tid & 31;
                int cb = (tid >> 5) * 16;
                const float* gp = M + (size_t)(kq * 32 + kl) * DD + cb;
                float* bp = U + kl * BQS + cb;
#pragma unroll
                for (int u = 0; u < 4; ++u)
                    *reinterpret_cast<float4*>(bp + 4 * u) =
                        *reinterpret_cast<const float4*>(gp + 4 * u);
            }
            __syncthreads();
#pragma unroll 2
            for (int kl = 0; kl < 32; ++kl) {
                int k = kq * 32 + kl;
                float4 a = *reinterpret_cast<const float4*>(&At[k * ATS + rg * 4]);
                float4 b0 = *reinterpret_cast<const float4*>(&U[kl * BQS + cg * 4]);
                float4 b1 = *reinterpret_cast<const float4*>(&U[kl * BQS + 64 + cg * 4]);
                float av[4] = {a.x, a.y, a.z, a.w};
                float bv[8] = {b0.x, b0.y, b0.z, b0.w, b1.x, b1.y, b1.z, b1.w};
#pragma unroll
                for (int i = 0; i < 4; ++i)
#pragma unroll
                    for (int j = 0; j < 8; ++j) acc[i][j] += av[i] * bv[j];
            }
            __syncthreads();
        }
    };

    // 1: AbY @ S1
    stageT(AbY);
    __syncthreads();
    gemm(S1, aS);

    // 2: AgY @ S2, then fold -AgY (transposed copy still in At)
    stageT(AgY);
    __syncthreads();
    gemm(S2, aS);
#pragma unroll
    for (int i = 0; i < 4; ++i) {
        int r = rg * 4 + i;
#pragma unroll
        for (int j = 0; j < 8; ++j) {
            int c = (j >> 2) * 64 + cg * 4 + (j & 3);
            aS[i][j] -= At[c * ATS + r];
        }
    }
    __syncthreads();

    // 3: Y @ P1, Y @ P2 (single staging of Y)
    stageT(Yc);
    __syncthreads();
    gemm(P1, aP1);
    gemm(P2, aP2);

    // 4: epilogue
    const float AL = 1.0f / 3.0f;
#pragma unroll
    for (int i = 0; i < 4; ++i) {
        int row = row0 + rg * 4 + i;
        if (row < n) {
            float dbv = db[row], dgv = dg[row];
            float aq = AL / (dbv + dgv + 1.0f);
#pragma unroll
            for (int hh = 0; hh < 2; ++hh) {
                size_t off = (size_t)row * DD + hh * 64 + cg * 4;
                float4 y = *reinterpret_cast<const float4*>(Yc + off);
                float4 x = *reinterpret_cast<const float4*>(X + off);
                float yv[4] = {y.x, y.y, y.z, y.w};
                float xv[4] = {x.x, x.y, x.z, x.w};
                float ov[4];
#pragma unroll
                for (int q = 0; q < 4; ++q) {
                    int j = hh * 4 + q;
                    float yhat = aS[i][j] + xv[q] + dgv * yv[q]
                                 - dbv * aP1[i][j] - dgv * aP2[i][j];
                    ov[q] = (1.0f - AL) * yv[q] + yhat * aq;
                }
                *reinterpret_cast<float4*>(Yn + off) = make_float4(ov[0], ov[1], ov[2], ov[3]);
            }
        }
    }
}

// ---------------- host ----------------

extern "C" void kernel_launch(void* const* d_in, const int* in_sizes, int n_in,
                              void* d_out, int out_size, void* d_ws, size_t ws_size,
                              hipStream_t stream) {
    const float* X   = (const float*)d_in[0];
    const float* H1  = (const float*)d_in[1];
    const float* H2  = (const float*)d_in[2];
    const float* wb  = (const float*)d_in[3];
    const float* wg  = (const float*)d_in[4];
    const float* db  = (const float*)d_in[5];
    const float* dg  = (const float*)d_in[6];
    const int* srcb  = (const int*)d_in[7];
    const int* dstb  = (const int*)d_in[8];
    const int* srcg  = (const int*)d_in[9];
    const int* dstg  = (const int*)d_in[10];
    const int N = in_sizes[5];
    const int E = in_sizes[3];
    float* Yout = (float*)d_out;

    char* p = (char*)d_ws;
    auto alloc = [&](size_t b) -> void* {
        void* r = (void*)p;
        p += (b + 255) & ~(size_t)255;
        return r;
    };
    float* P1 = (float*)alloc((size_t)DD * DD * 4);
    float* S1 = (float*)alloc((size_t)DD * DD * 4);
    float* P2 = (float*)alloc((size_t)DD * DD * 4);
    float* S2 = (float*)alloc((size_t)DD * DD * 4);
    int* degb = (int*)alloc((size_t)N * 4);
    int* degg = (int*)alloc((size_t)N * 4);
    int* rpb  = (int*)alloc((size_t)(N + 1) * 4);
    int* rpg  = (int*)alloc((size_t)(N + 1) * 4);
    int* curb = (int*)alloc((size_t)N * 4);
    int* curg = (int*)alloc((size_t)N * 4);
    int2* eb  = (int2*)alloc((size_t)E * 8);
    int2* eg  = (int2*)alloc((size_t)E * 8);
    float* AbY = (float*)alloc((size_t)N * DD * 4);
    float* AgY = (float*)alloc((size_t)N * DD * 4);
    float* Yw  = (float*)alloc((size_t)N * DD * 4);

    hipMemsetAsync(degb, 0, (size_t)N * 4, stream);
    hipMemsetAsync(degg, 0, (size_t)N * 4, stream);

    int gE = (E + 255) / 256;
    count2_k<<<2 * gE, 256, 0, stream>>>(dstb, dstg, degb, degg, E, gE);
    scan2_k<<<2, 1024, 0, stream>>>(degb, degg, rpb, rpg, curb, curg, N);
    fill2_k<<<2 * gE, 256, 0, stream>>>(srcb, dstb, wb, srcg, dstg, wg,
                                        curb, curg, eb, eg, E, gE);
    prep_k<<<64, 256, 0, stream>>>(H1, P1, S1);
    prep_k<<<64, 256, 0, stream>>>(H2, P2, S2);

    const float* Ycur = X;
    float* Ybufs[2] = {Yw, Yout};
    int gs = (N + 3) / 4;
    int gd = (N + 63) / 64;
    for (int s = 0; s < 8; ++s) {
        float* Yn = Ybufs[s & 1];
        spmm2_k<<<gs, 256, 0, stream>>>(rpb, eb, rpg, eg, Ycur, AbY, AgY, N);
        dense4_k<<<gd, 256, 0, stream>>>(Ycur, X, AbY, AgY, db, dg,
                                         P1, P2, S1, S2, Yn, N);
        Ycur = Yn;
    }
}

// Round 8
// 3915.552 us; speedup vs baseline: 2.4818x; 1.0099x over previous
//
#include <hip/hip_runtime.h>
#include <cstdint>
#include <cstddef>

#define DD 128
#define ATS 68    // At row stride (64 rows + 4 pad)
#define BQS 132   // B-quarter row stride

// ---------------- CSR build (both graphs in one launch) ----------------

__global__ void count2_k(const int* __restrict__ dstb, const int* __restrict__ dstg,
                         int* __restrict__ degb, int* __restrict__ degg, int E, int gE) {
    int b = blockIdx.x;
    const int* dst = (b < gE) ? dstb : dstg;
    int* deg = (b < gE) ? degb : degg;
    int i = ((b < gE) ? b : b - gE) * blockDim.x + threadIdx.x;
    if (i < E) atomicAdd(&deg[dst[i]], 1);
}

__global__ __launch_bounds__(1024) void scan2_k(const int* __restrict__ degb,
                                                const int* __restrict__ degg,
                                                int* __restrict__ rpb, int* __restrict__ rpg,
                                                int* __restrict__ curb, int* __restrict__ curg,
                                                int n) {
    const int* deg = (blockIdx.x == 0) ? degb : degg;
    int* rp = (blockIdx.x == 0) ? rpb : rpg;
    int* cur = (blockIdx.x == 0) ? curb : curg;
    __shared__ int sums[1024];
    int tid = threadIdx.x;
    int per = (n + 1023) >> 10;
    int start = tid * per;
    int end = min(start + per, n);
    int s = 0;
    for (int i = start; i < end; ++i) s += deg[i];
    sums[tid] = s;
    __syncthreads();
    for (int off = 1; off < 1024; off <<= 1) {
        int v = (tid >= off) ? sums[tid - off] : 0;
        __syncthreads();
        sums[tid] += v;
        __syncthreads();
    }
    int pre = (tid == 0) ? 0 : sums[tid - 1];
    for (int i = start; i < end; ++i) {
        rp[i] = pre;
        cur[i] = pre;
        pre += deg[i];
    }
    if (end == n) rp[n] = pre;
}

__global__ void fill2_k(const int* __restrict__ srcb, const int* __restrict__ dstb,
                        const float* __restrict__ wb,
                        const int* __restrict__ srcg, const int* __restrict__ dstg,
                        const float* __restrict__ wg,
                        int* __restrict__ curb, int* __restrict__ curg,
                        int2* __restrict__ eb, int2* __restrict__ eg, int E, int gE) {
    int b = blockIdx.x;
    bool isb = (b < gE);
    const int* src = isb ? srcb : srcg;
    const int* dst = isb ? dstb : dstg;
    const float* w = isb ? wb : wg;
    int* cur = isb ? curb : curg;
    int2* edges = isb ? eb : eg;
    int i = (isb ? b : b - gE) * blockDim.x + threadIdx.x;
    if (i < E) {
        int d = dst[i];
        int pos = atomicAdd(&cur[d], 1);
        edges[pos] = make_int2(src[i], __float_as_int(w[i]));
    }
}

// ---------------- P = H H^T, S = H + H^T ----------------

__global__ __launch_bounds__(256) void prep_k(const float* __restrict__ H,
                                              float* __restrict__ P,
                                              float* __restrict__ S) {
    int idx = blockIdx.x * 256 + threadIdx.x;
    int i = idx >> 7, j = idx & 127;
    float acc = 0.f;
    for (int k = 0; k < DD; ++k) acc += H[i * DD + k] * H[j * DD + k];
    P[idx] = acc;
    S[idx] = H[i * DD + j] + H[j * DD + i];
}

// ---------------- spmm2: both graphs, interleaved gather chains (unchanged, r7) ----------------

__global__ __launch_bounds__(256, 8) void spmm2_k(
    const int* __restrict__ rpb, const int2* __restrict__ eb,
    const int* __restrict__ rpg, const int2* __restrict__ eg,
    const float* __restrict__ Y,
    float* __restrict__ outb, float* __restrict__ outg, int n)
{
    int node = blockIdx.x * 4 + (threadIdx.x >> 6);
    if (node >= n) return;
    int lane = threadIdx.x & 63;

    int jb = rpb[node], be = rpb[node + 1];
    int jg = rpg[node], ge = rpg[node + 1];
    float b0 = 0.f, b1 = 0.f, g0 = 0.f, g1 = 0.f;

    while (jb + 4 <= be && jg + 4 <= ge) {
        int2 x0 = eb[jb + 0], x1 = eb[jb + 1], x2 = eb[jb + 2], x3 = eb[jb + 3];
        int2 y0 = eg[jg + 0], y1 = eg[jg + 1], y2 = eg[jg + 2], y3 = eg[jg + 3];
        float2 fb0 = *((const float2*)(Y + (size_t)x0.x * DD) + lane);
        float2 fb1 = *((const float2*)(Y + (size_t)x1.x * DD) + lane);
        float2 fb2 = *((const float2*)(Y + (size_t)x2.x * DD) + lane);
        float2 fb3 = *((const float2*)(Y + (size_t)x3.x * DD) + lane);
        float2 fg0 = *((const float2*)(Y + (size_t)y0.x * DD) + lane);
        float2 fg1 = *((const float2*)(Y + (size_t)y1.x * DD) + lane);
        float2 fg2 = *((const float2*)(Y + (size_t)y2.x * DD) + lane);
        float2 fg3 = *((const float2*)(Y + (size_t)y3.x * DD) + lane);
        float wb0 = __int_as_float(x0.y), wb1 = __int_as_float(x1.y);
        float wb2 = __int_as_float(x2.y), wb3 = __int_as_float(x3.y);
        float wg0 = __int_as_float(y0.y), wg1 = __int_as_float(y1.y);
        float wg2 = __int_as_float(y2.y), wg3 = __int_as_float(y3.y);
        b0 += wb0 * fb0.x; b1 += wb0 * fb0.y;
        b0 += wb1 * fb1.x; b1 += wb1 * fb1.y;
        b0 += wb2 * fb2.x; b1 += wb2 * fb2.y;
        b0 += wb3 * fb3.x; b1 += wb3 * fb3.y;
        g0 += wg0 * fg0.x; g1 += wg0 * fg0.y;
        g0 += wg1 * fg1.x; g1 += wg1 * fg1.y;
        g0 += wg2 * fg2.x; g1 += wg2 * fg2.y;
        g0 += wg3 * fg3.x; g1 += wg3 * fg3.y;
        jb += 4; jg += 4;
    }
    while (jb + 4 <= be) {
        int2 x0 = eb[jb + 0], x1 = eb[jb + 1], x2 = eb[jb + 2], x3 = eb[jb + 3];
        float2 f0 = *((const float2*)(Y + (size_t)x0.x * DD) + lane);
        float2 f1 = *((const float2*)(Y + (size_t)x1.x * DD) + lane);
        float2 f2 = *((const float2*)(Y + (size_t)x2.x * DD) + lane);
        float2 f3 = *((const float2*)(Y + (size_t)x3.x * DD) + lane);
        float w0 = __int_as_float(x0.y), w1 = __int_as_float(x1.y);
        float w2 = __int_as_float(x2.y), w3 = __int_as_float(x3.y);
        b0 += w0 * f0.x; b1 += w0 * f0.y;
        b0 += w1 * f1.x; b1 += w1 * f1.y;
        b0 += w2 * f2.x; b1 += w2 * f2.y;
        b0 += w3 * f3.x; b1 += w3 * f3.y;
        jb += 4;
    }
    while (jg + 4 <= ge) {
        int2 y0 = eg[jg + 0], y1 = eg[jg + 1], y2 = eg[jg + 2], y3 = eg[jg + 3];
        float2 f0 = *((const float2*)(Y + (size_t)y0.x * DD) + lane);
        float2 f1 = *((const float2*)(Y + (size_t)y1.x * DD) + lane);
        float2 f2 = *((const float2*)(Y + (size_t)y2.x * DD) + lane);
        float2 f3 = *((const float2*)(Y + (size_t)y3.x * DD) + lane);
        float w0 = __int_as_float(y0.y), w1 = __int_as_float(y1.y);
        float w2 = __int_as_float(y2.y), w3 = __int_as_float(y3.y);
        g0 += w0 * f0.x; g1 += w0 * f0.y;
        g0 += w1 * f1.x; g1 += w1 * f1.y;
        g0 += w2 * f2.x; g1 += w2 * f2.y;
        g0 += w3 * f3.x; g1 += w3 * f3.y;
        jg += 4;
    }
    for (; jb < be; ++jb) {
        int2 e = eb[jb];
        float2 f = *((const float2*)(Y + (size_t)e.x * DD) + lane);
        float wv = __int_as_float(e.y);
        b0 += wv * f.x; b1 += wv * f.y;
    }
    for (; jg < ge; ++jg) {
        int2 e = eg[jg];
        float2 f = *((const float2*)(Y + (size_t)e.x * DD) + lane);
        float wv = __int_as_float(e.y);
        g0 += wv * f.x; g1 += wv * f.y;
    }
    *((float2*)(outb + (size_t)node * DD) + lane) = make_float2(b0, b1);
    *((float2*)(outg + (size_t)node * DD) + lane) = make_float2(g0, g1);
}

// ---------------- dense4 v2: reg-prefetched B, merged P-pass, single accumulator ----------------
// acc = X + dg*Y - db*(Y@P1) - dg*(Y@P2)      (P-phase, merged)
// acc += AbY@S1 ; acc += AgY@S2 ; acc -= AgY
// Yn = (2/3)Y + (1/3)*acc/(db+dg+1)

__global__ __launch_bounds__(256, 3) void dense4_k(
    const float* __restrict__ Yc, const float* __restrict__ X,
    const float* __restrict__ AbY, const float* __restrict__ AgY,
    const float* __restrict__ db, const float* __restrict__ dg,
    const float* __restrict__ P1, const float* __restrict__ P2,
    const float* __restrict__ S1, const float* __restrict__ S2,
    float* __restrict__ Yn, int n)
{
    __shared__ float At[DD * ATS];
    __shared__ float U[32 * BQS];

    const int tid = threadIdx.x;
    const int cg = tid & 15;
    const int rg = tid >> 4;
    const int row0 = blockIdx.x * 64;

    auto stageT = [&](const float* __restrict__ G) {
        int r = tid >> 2;
        int rowc = min(row0 + r, n - 1);
        const float* gp = G + (size_t)rowc * DD;
#pragma unroll
        for (int i = 0; i < 8; ++i) {
            int c = ((tid & 3) << 2) + (i << 4);
            float4 v = *reinterpret_cast<const float4*>(gp + c);
            At[(c + 0) * ATS + r] = v.x;
            At[(c + 1) * ATS + r] = v.y;
            At[(c + 2) * ATS + r] = v.z;
            At[(c + 3) * ATS + r] = v.w;
        }
    };

    // ---------- Phase P: merged Y@P1, Y@P2 with reg-prefetch ----------
    float aP1[4][8], aP2[4][8];
#pragma unroll
    for (int i = 0; i < 4; ++i)
#pragma unroll
        for (int j = 0; j < 8; ++j) { aP1[i][j] = 0.f; aP2[i][j] = 0.f; }

    stageT(Yc);

    {
        const int kl = tid >> 4;          // 0..15
        const int cb = (tid & 15) * 8;    // 0..120
        float4 p1a, p1b, p2a, p2b;
        {
            const float* g1 = P1 + (size_t)kl * DD + cb;
            const float* g2 = P2 + (size_t)kl * DD + cb;
            p1a = *reinterpret_cast<const float4*>(g1);
            p1b = *reinterpret_cast<const float4*>(g1 + 4);
            p2a = *reinterpret_cast<const float4*>(g2);
            p2b = *reinterpret_cast<const float4*>(g2 + 4);
        }
#pragma unroll 1
        for (int ph = 0; ph < 8; ++ph) {
            __syncthreads();   // U free (and, at ph=0, At(Y) staged)
            {
                float* b1 = U + kl * BQS + cb;
                float* b2 = U + (16 + kl) * BQS + cb;
                *reinterpret_cast<float4*>(b1) = p1a;
                *reinterpret_cast<float4*>(b1 + 4) = p1b;
                *reinterpret_cast<float4*>(b2) = p2a;
                *reinterpret_cast<float4*>(b2 + 4) = p2b;
            }
            __syncthreads();   // U ready
            if (ph < 7) {
                const float* g1 = P1 + (size_t)((ph + 1) * 16 + kl) * DD + cb;
                const float* g2 = P2 + (size_t)((ph + 1) * 16 + kl) * DD + cb;
                p1a = *reinterpret_cast<const float4*>(g1);
                p1b = *reinterpret_cast<const float4*>(g1 + 4);
                p2a = *reinterpret_cast<const float4*>(g2);
                p2b = *reinterpret_cast<const float4*>(g2 + 4);
            }
#pragma unroll 2
            for (int k2 = 0; k2 < 16; ++k2) {
                int k = ph * 16 + k2;
                float4 a = *reinterpret_cast<const float4*>(&At[k * ATS + rg * 4]);
                float4 b10 = *reinterpret_cast<const float4*>(&U[k2 * BQS + cg * 4]);
                float4 b11 = *reinterpret_cast<const float4*>(&U[k2 * BQS + 64 + cg * 4]);
                float4 b20 = *reinterpret_cast<const float4*>(&U[(16 + k2) * BQS + cg * 4]);
                float4 b21 = *reinterpret_cast<const float4*>(&U[(16 + k2) * BQS + 64 + cg * 4]);
                float av[4] = {a.x, a.y, a.z, a.w};
                float b1v[8] = {b10.x, b10.y, b10.z, b10.w, b11.x, b11.y, b11.z, b11.w};
                float b2v[8] = {b20.x, b20.y, b20.z, b20.w, b21.x, b21.y, b21.z, b21.w};
#pragma unroll
                for (int i = 0; i < 4; ++i)
#pragma unroll
                    for (int j = 0; j < 8; ++j) {
                        aP1[i][j] += av[i] * b1v[j];
                        aP2[i][j] += av[i] * b2v[j];
                    }
            }
        }
        __syncthreads();   // all U/At reads done
    }

    // ---------- Fold: acc = X + dg*Y - db*aP1 - dg*aP2 (aP1 becomes acc) ----------
#pragma unroll
    for (int i = 0; i < 4; ++i) {
        int rowc = min(row0 + rg * 4 + i, n - 1);
        float dbv = db[rowc], dgv = dg[rowc];
#pragma unroll
        for (int hh = 0; hh < 2; ++hh) {
            size_t off = (size_t)rowc * DD + hh * 64 + cg * 4;
            float4 y = *reinterpret_cast<const float4*>(Yc + off);
            float4 x = *reinterpret_cast<const float4*>(X + off);
            float yv[4] = {y.x, y.y, y.z, y.w};
            float xv[4] = {x.x, x.y, x.z, x.w};
#pragma unroll
            for (int q = 0; q < 4; ++q) {
                int j = hh * 4 + q;
                aP1[i][j] = xv[q] + dgv * yv[q] - dbv * aP1[i][j] - dgv * aP2[i][j];
            }
        }
    }

    // ---------- gemm1 with reg-prefetch (acc += A@M), A staged in At ----------
    auto gemm1 = [&](const float* __restrict__ M, float (&acc)[4][8]) {
        const int kl = tid & 31;
        const int cb = (tid >> 5) * 16;
        float4 pa, pb, pc, pd;
        {
            const float* gp = M + (size_t)kl * DD + cb;
            pa = *reinterpret_cast<const float4*>(gp);
            pb = *reinterpret_cast<const float4*>(gp + 4);
            pc = *reinterpret_cast<const float4*>(gp + 8);
            pd = *reinterpret_cast<const float4*>(gp + 12);
        }
#pragma unroll 1
        for (int kq = 0; kq < 4; ++kq) {
            __syncthreads();
            {
                float* bp = U + kl * BQS + cb;
                *reinterpret_cast<float4*>(bp) = pa;
                *reinterpret_cast<float4*>(bp + 4) = pb;
                *reinterpret_cast<float4*>(bp + 8) = pc;
                *reinterpret_cast<float4*>(bp + 12) = pd;
            }
            __syncthreads();
            if (kq < 3) {
                const float* gp = M + (size_t)((kq + 1) * 32 + kl) * DD + cb;
                pa = *reinterpret_cast<const float4*>(gp);
                pb = *reinterpret_cast<const float4*>(gp + 4);
                pc = *reinterpret_cast<const float4*>(gp + 8);
                pd = *reinterpret_cast<const float4*>(gp + 12);
            }
#pragma unroll 2
            for (int k2 = 0; k2 < 32; ++k2) {
                int k = kq * 32 + k2;
                float4 a = *reinterpret_cast<const float4*>(&At[k * ATS + rg * 4]);
                float4 b0 = *reinterpret_cast<const float4*>(&U[k2 * BQS + cg * 4]);
                float4 b1 = *reinterpret_cast<const float4*>(&U[k2 * BQS + 64 + cg * 4]);
                float av[4] = {a.x, a.y, a.z, a.w};
                float bv[8] = {b0.x, b0.y, b0.z, b0.w, b1.x, b1.y, b1.z, b1.w};
#pragma unroll
                for (int i = 0; i < 4; ++i)
#pragma unroll
                    for (int j = 0; j < 8; ++j) acc[i][j] += av[i] * bv[j];
            }
        }
        __syncthreads();
    };

    // ---------- Phase S1: acc += AbY@S1 ----------
    stageT(AbY);            // gemm1's first barrier makes this visible
    gemm1(S1, aP1);

    // ---------- Phase S2: acc += AgY@S2, then acc -= AgY ----------
    stageT(AgY);
    gemm1(S2, aP1);
#pragma unroll
    for (int i = 0; i < 4; ++i) {
        int r = rg * 4 + i;
#pragma unroll
        for (int j = 0; j < 8; ++j) {
            int c = (j >> 2) * 64 + cg * 4 + (j & 3);
            aP1[i][j] -= At[c * ATS + r];
        }
    }

    // ---------- Epilogue ----------
    const float AL = 1.0f / 3.0f;
#pragma unroll
    for (int i = 0; i < 4; ++i) {
        int row = row0 + rg * 4 + i;
        if (row < n) {
            float dbv = db[row], dgv = dg[row];
            float aq = AL / (dbv + dgv + 1.0f);
#pragma unroll
            for (int hh = 0; hh < 2; ++hh) {
                size_t off = (size_t)row * DD + hh * 64 + cg * 4;
                float4 y = *reinterpret_cast<const float4*>(Yc + off);
                float yv[4] = {y.x, y.y, y.z, y.w};
                float ov[4];
#pragma unroll
                for (int q = 0; q < 4; ++q) {
                    int j = hh * 4 + q;
                    ov[q] = (1.0f - AL) * yv[q] + aP1[i][j] * aq;
                }
                *reinterpret_cast<float4*>(Yn + off) = make_float4(ov[0], ov[1], ov[2], ov[3]);
            }
        }
    }
}

// ---------------- host ----------------

extern "C" void kernel_launch(void* const* d_in, const int* in_sizes, int n_in,
                              void* d_out, int out_size, void* d_ws, size_t ws_size,
                              hipStream_t stream) {
    const float* X   = (const float*)d_in[0];
    const float* H1  = (const float*)d_in[1];
    const float* H2  = (const float*)d_in[2];
    const float* wb  = (const float*)d_in[3];
    const float* wg  = (const float*)d_in[4];
    const float* db  = (const float*)d_in[5];
    const float* dg  = (const float*)d_in[6];
    const int* srcb  = (const int*)d_in[7];
    const int* dstb  = (const int*)d_in[8];
    const int* srcg  = (const int*)d_in[9];
    const int* dstg  = (const int*)d_in[10];
    const int N = in_sizes[5];
    const int E = in_sizes[3];
    float* Yout = (float*)d_out;

    char* p = (char*)d_ws;
    auto alloc = [&](size_t b) -> void* {
        void* r = (void*)p;
        p += (b + 255) & ~(size_t)255;
        return r;
    };
    float* P1 = (float*)alloc((size_t)DD * DD * 4);
    float* S1 = (float*)alloc((size_t)DD * DD * 4);
    float* P2 = (float*)alloc((size_t)DD * DD * 4);
    float* S2 = (float*)alloc((size_t)DD * DD * 4);
    int* degb = (int*)alloc((size_t)N * 4);
    int* degg = (int*)alloc((size_t)N * 4);
    int* rpb  = (int*)alloc((size_t)(N + 1) * 4);
    int* rpg  = (int*)alloc((size_t)(N + 1) * 4);
    int* curb = (int*)alloc((size_t)N * 4);
    int* curg = (int*)alloc((size_t)N * 4);
    int2* eb  = (int2*)alloc((size_t)E * 8);
    int2* eg  = (int2*)alloc((size_t)E * 8);
    float* AbY = (float*)alloc((size_t)N * DD * 4);
    float* AgY = (float*)alloc((size_t)N * DD * 4);
    float* Yw  = (float*)alloc((size_t)N * DD * 4);

    hipMemsetAsync(degb, 0, (size_t)N * 4, stream);
    hipMemsetAsync(degg, 0, (size_t)N * 4, stream);

    int gE = (E + 255) / 256;
    count2_k<<<2 * gE, 256, 0, stream>>>(dstb, dstg, degb, degg, E, gE);
    scan2_k<<<2, 1024, 0, stream>>>(degb, degg, rpb, rpg, curb, curg, N);
    fill2_k<<<2 * gE, 256, 0, stream>>>(srcb, dstb, wb, srcg, dstg, wg,
                                        curb, curg, eb, eg, E, gE);
    prep_k<<<64, 256, 0, stream>>>(H1, P1, S1);
    prep_k<<<64, 256, 0, stream>>>(H2, P2, S2);

    const float* Ycur = X;
    float* Ybufs[2] = {Yw, Yout};
    int gs = (N + 3) / 4;
    int gd = (N + 63) / 64;
    for (int s = 0; s < 8; ++s) {
        float* Yn = Ybufs[s & 1];
        spmm2_k<<<gs, 256, 0, stream>>>(rpb, eb, rpg, eg, Ycur, AbY, AgY, N);
        dense4_k<<<gd, 256, 0, stream>>>(Ycur, X, AbY, AgY, db, dg,
                                         P1, P2, S1, S2, Yn, N);
        Ycur = Yn;
    }
}